// Round 18
// baseline (95.642 us; speedup 1.0000x reference)
//
#include <hip/hip_runtime.h>

typedef __attribute__((ext_vector_type(8))) short short8;
typedef __attribute__((ext_vector_type(16))) float f32x16;

#define NROWS 32768        // B*H*W
#define NELEM 262144       // B*C*H*W
#define KCB   8192
#define ROWS_PB 32         // rows per block (one 32-row MFMA tile)
#define NWAVE 8            // k-waves per block; each scans KCB/8 = 1024 entries

// round-to-nearest-even fp32 -> bf16 (A-side, unchanged from all rounds)
static __device__ __forceinline__ short to_bf16(float x) {
    unsigned u = __float_as_uint(x);
    unsigned r = (u + 0x7FFFu + ((u >> 16) & 1u)) >> 16;
    return (short)r;
}

// trunc-pack 2 fp32 -> (hi16|lo16) 2xbf16 word (B-side; trunc-vs-RNE only
// flips near-ties -> err <= codebook diameter 2.4e-4 << 2.5e-2 threshold)
static __device__ __forceinline__ unsigned pk2(float lo, float hi) {
    return (__float_as_uint(hi) & 0xFFFF0000u) | (__float_as_uint(lo) >> 16);
}
static __device__ __forceinline__ short8 pack8(float4 a, float4 b) {
    int4 d = { (int)pk2(a.x, a.y), (int)pk2(a.z, a.w),
               (int)pk2(b.x, b.y), (int)pk2(b.z, b.w) };
    short8 s;
    __builtin_memcpy(&s, &d, 16);
    return s;
}

// 3-inst pack+merge: best = max3((s0&M)|iv0, (s1&M)|iv1, best)
static __device__ __forceinline__ void packmax3(float& best, float s0, float s1,
                                                unsigned iv0, unsigned iv1)
{
    float p0, p1;
    asm("v_and_or_b32 %0, %1, %2, %3"
        : "=v"(p0) : "v"(s0), "s"(0xFFFFE000u), "v"(iv0));
    asm("v_and_or_b32 %0, %1, %2, %3"
        : "=v"(p1) : "v"(s1), "s"(0xFFFFE000u), "v"(iv1));
    asm("v_max3_f32 %0, %1, %2, %0"
        : "+v"(best) : "v"(p0), "v"(p1));
}

// FULLY FUSED (no prep, no workspace): 1024 blocks x 512 thr (8 k-waves),
// 32 rows/block, 32x32x16 MFMA, R11 2-slot pipeline. B-frags built in-kernel
// from the PRISTINE fp32 codebook (read-only across replays -> clean lines in
// every XCD L2, unlike the replay-dirty cbb workspace). hi=1 lanes' raw regs
// are zero-init and never written (exec-masked loads) -> k=8..15 stay zero.
__global__ __launch_bounds__(512, 4) void vq_all(
    const float* __restrict__ z, const float* __restrict__ cb,
    float* __restrict__ out)
{
    __shared__ float sbest[NWAVE][ROWS_PB];
    __shared__ float lsum[NWAVE];

    const int tid  = threadIdx.x;
    const int lane = tid & 63;
    const int w    = tid >> 6;            // k-wave 0..7
    const int c32  = lane & 31;
    const int hi   = lane >> 5;

    const int row0 = blockIdx.x * ROWS_PB;

    // ---- A frag: hi=0 lanes = row c32 channels (k0..7, RNE); hi=1 = zeros ----
    short8 af = {0, 0, 0, 0, 0, 0, 0, 0};
    if (hi == 0) {
        const int row = row0 + c32;
        const float* zr = z + (size_t)(row >> 12) * 32768 + (row & 4095);
        af[0] = to_bf16(zr[0]);     af[1] = to_bf16(zr[4096]);
        af[2] = to_bf16(zr[8192]);  af[3] = to_bf16(zr[12288]);
        af[4] = to_bf16(zr[16384]); af[5] = to_bf16(zr[20480]);
        af[6] = to_bf16(zr[24576]); af[7] = to_bf16(zr[28672]);
    }

    const int kbase = w * (KCB / NWAVE);  // 1024 entries = 32 tiles = 16 pairs
    const float4* bp = (const float4*)cb + (size_t)(kbase + c32) * 2;
    // tile t -> entries kbase + t*32 + c32 -> float4 offset t*64

    float best[16];
    #pragma unroll
    for (int r = 0; r < 16; ++r)
        best[r] = __uint_as_float(0xFF800000u);   // -inf

    const f32x16 z16 = {0.f,0.f,0.f,0.f,0.f,0.f,0.f,0.f,
                        0.f,0.f,0.f,0.f,0.f,0.f,0.f,0.f};

    // raw B slots; zero-init so hi=1 lanes contribute zero k=8..15 forever
    const float4 f4z = {0.f, 0.f, 0.f, 0.f};
    float4 rA0a = f4z, rA0b = f4z, rA1a = f4z, rA1b = f4z;
    float4 rB0a = f4z, rB0b = f4z, rB1a = f4z, rB1b = f4z;

#define LD2(Xa, Xb, T)                                                \
    if (hi == 0) {                                                    \
        Xa = bp[(size_t)(T) * 64];                                    \
        Xb = bp[(size_t)(T) * 64 + 1];                                \
    }
#define PACK16(D0, D1, IV)                                            \
    {   const unsigned iv0_ = (IV), iv1_ = (IV) - 32u;                \
        _Pragma("unroll")                                             \
        for (int r = 0; r < 16; ++r)                                  \
            packmax3(best[r], (D0)[r], (D1)[r], iv0_, iv1_);          }

    unsigned ivA = 8191u - (unsigned)kbase - (unsigned)c32;  // even pairs
    unsigned ivB = ivA - 64u;                                // odd pairs

    // ---- prologue: pairs 0 (A-slot) and 1 (B-slot) ----
    LD2(rA0a, rA0b, 0); LD2(rA1a, rA1b, 1);
    LD2(rB0a, rB0b, 2); LD2(rB1a, rB1b, 3);
    f32x16 dA0 = __builtin_amdgcn_mfma_f32_32x32x16_bf16(af, pack8(rA0a, rA0b), z16, 0, 0, 0);
    f32x16 dA1 = __builtin_amdgcn_mfma_f32_32x32x16_bf16(af, pack8(rA1a, rA1b), z16, 0, 0, 0);
    LD2(rA0a, rA0b, 4); LD2(rA1a, rA1b, 5);

    // ---- steady state: iter i packs pairs 2i and 2i+1 ----
    #pragma unroll 1
    for (int i = 0; i < 7; ++i) {
        f32x16 dB0 = __builtin_amdgcn_mfma_f32_32x32x16_bf16(af, pack8(rB0a, rB0b), z16, 0, 0, 0);
        f32x16 dB1 = __builtin_amdgcn_mfma_f32_32x32x16_bf16(af, pack8(rB1a, rB1b), z16, 0, 0, 0);
        LD2(rB0a, rB0b, 4 * i + 6); LD2(rB1a, rB1b, 4 * i + 7);
        PACK16(dA0, dA1, ivA);                 // covers dB latency
        ivA -= 128u;
        dA0 = __builtin_amdgcn_mfma_f32_32x32x16_bf16(af, pack8(rA0a, rA0b), z16, 0, 0, 0);
        dA1 = __builtin_amdgcn_mfma_f32_32x32x16_bf16(af, pack8(rA1a, rA1b), z16, 0, 0, 0);
        LD2(rA0a, rA0b, (4 * i + 8) & 31);     // i=6 wraps -> dead load, harmless
        LD2(rA1a, rA1b, (4 * i + 9) & 31);
        PACK16(dB0, dB1, ivB);                 // covers dA latency
        ivB -= 128u;
    }

    // ---- epilogue: pairs 14 (in dA) and 15 (in B slots) ----
    {
        f32x16 dB0 = __builtin_amdgcn_mfma_f32_32x32x16_bf16(af, pack8(rB0a, rB0b), z16, 0, 0, 0);
        f32x16 dB1 = __builtin_amdgcn_mfma_f32_32x32x16_bf16(af, pack8(rB1a, rB1b), z16, 0, 0, 0);
        PACK16(dA0, dA1, ivA);
        PACK16(dB0, dB1, ivB);
    }

    // ---- reduce over 32 entry-cols ----
    #pragma unroll
    for (int d = 1; d < 32; d <<= 1)
        #pragma unroll
        for (int r = 0; r < 16; ++r)
            best[r] = fmaxf(best[r], __shfl_xor(best[r], d));

    if (c32 == 0) {
        #pragma unroll
        for (int r = 0; r < 16; ++r) {
            const int m = (r & 3) + ((r >> 2) << 3) + (hi << 2);  // C/D row map (verified)
            sbest[w][m] = best[r];
        }
    }
    __syncthreads();

    // ---- emit: 32 rows x 8 ch, one elem/thread (first 256 threads) ----
    float sq = 0.0f;
    if (tid < 256) {
        const int pos = tid & 31;
        const int ch  = tid >> 5;
        float m = sbest[0][pos];
        #pragma unroll
        for (int kw = 1; kw < NWAVE; ++kw) m = fmaxf(m, sbest[kw][pos]);
        const int k = 8191 - (int)(__float_as_uint(m) & 8191u);

        const int n = row0 + pos;
        const size_t o = ((size_t)(n >> 12)) * 32768 + (size_t)ch * 4096
                       + (size_t)(n & 4095);
        float ev = cb[(size_t)k * 8 + ch];
        float zz = z[o];
        out[o] = ev;
        float dd = ev - zz;
        sq = dd * dd;
    }
    #pragma unroll
    for (int off = 32; off > 0; off >>= 1) sq += __shfl_down(sq, off);
    if (lane == 0) lsum[w] = sq;
    __syncthreads();
    if (tid == 0) {
        float s = 0.f;
        #pragma unroll
        for (int kw = 0; kw < NWAVE; ++kw) s += lsum[kw];
        atomicAdd(out + NELEM, s * (1.25f / (float)NELEM));
    }
}

extern "C" void kernel_launch(void* const* d_in, const int* in_sizes, int n_in,
                              void* d_out, int out_size, void* d_ws, size_t ws_size,
                              hipStream_t stream)
{
    const float* z  = (const float*)d_in[0];   // [8, 8, 64, 64] fp32
    const float* cb = (const float*)d_in[1];   // [8192, 8] fp32
    float* out = (float*)d_out;                // 262144 z_q + 1 loss

    hipMemsetAsync(out + NELEM, 0, sizeof(float), stream);
    vq_all<<<NROWS / ROWS_PB, 512, 0, stream>>>(z, cb, out);
}

// Round 19
// 33.506 us; speedup vs baseline: 2.8545x; 2.8545x over previous
//
#include <hip/hip_runtime.h>

typedef __attribute__((ext_vector_type(8))) short short8;
typedef __attribute__((ext_vector_type(16))) float f32x16;

#define NROWS 32768        // B*H*W
#define NELEM 262144       // B*C*H*W
#define KCB   8192
#define ROWS_PB 32         // rows per block (one 32-row MFMA tile)
#define NWAVE 8            // k-waves per block; each scans KCB/8 = 1024 entries

// round-to-nearest-even fp32 -> bf16 (finite values only)
static __device__ __forceinline__ short to_bf16(float x) {
    unsigned u = __float_as_uint(x);
    unsigned r = (u + 0x7FFFu + ((u >> 16) & 1u)) >> 16;
    return (short)r;
}

// Prep (R8/R10-verified layout): codebook group g (32 entries) = 1KB:
// bytes [0,512) = entries' ch0..7 (16B each, k=0..7),
// bytes [512,1024) = entries' [-0.5*||e||^2, 0 x7] (k=8..15).
// Also pack z rows (8 bf16) and zero the loss slot.
__global__ __launch_bounds__(256) void vq_prep(
    const float* __restrict__ z, const float* __restrict__ cb,
    short8* __restrict__ cbb32, short8* __restrict__ pka, float* __restrict__ out)
{
    int gid = blockIdx.x * 256 + threadIdx.x;
    if (gid == 0) out[NELEM] = 0.0f;
    if (gid < KCB) {
        const float4* p = (const float4*)(cb + (size_t)gid * 8);
        float4 a = p[0], b = p[1];
        float h = -0.5f * (a.x*a.x + a.y*a.y + a.z*a.z + a.w*a.w
                         + b.x*b.x + b.y*b.y + b.z*b.z + b.w*b.w);
        short8 lo = { to_bf16(a.x), to_bf16(a.y), to_bf16(a.z), to_bf16(a.w),
                      to_bf16(b.x), to_bf16(b.y), to_bf16(b.z), to_bf16(b.w) };
        short8 hi = { to_bf16(h), 0, 0, 0, 0, 0, 0, 0 };
        cbb32[(gid >> 5) * 64 + (gid & 31)]      = lo;
        cbb32[(gid >> 5) * 64 + 32 + (gid & 31)] = hi;
    } else {
        int n = gid - KCB;
        int bb = n >> 12, hw = n & 4095;
        const float* zp = z + (size_t)bb * 32768 + hw;
        short8 v = { to_bf16(zp[0]),     to_bf16(zp[4096]),
                     to_bf16(zp[8192]),  to_bf16(zp[12288]),
                     to_bf16(zp[16384]), to_bf16(zp[20480]),
                     to_bf16(zp[24576]), to_bf16(zp[28672]) };
        pka[n] = v;
    }
}

// 3-inst pack+merge: best = max3((s0&M)|iv0, (s1&M)|iv1, best)
static __device__ __forceinline__ void packmax3(float& best, float s0, float s1,
                                                unsigned iv0, unsigned iv1)
{
    float p0, p1;
    asm("v_and_or_b32 %0, %1, %2, %3"
        : "=v"(p0) : "v"(s0), "s"(0xFFFFE000u), "v"(iv0));
    asm("v_and_or_b32 %0, %1, %2, %3"
        : "=v"(p1) : "v"(s1), "s"(0xFFFFE000u), "v"(iv1));
    asm("v_max3_f32 %0, %1, %2, %0"
        : "+v"(best) : "v"(p0), "v"(p1));
}

// Scan: 1024 blocks x 512 thr (8 k-waves), 32 rows/block, 32x32x16 MFMA.
// Explicit 2-slot in-wave pipeline: pair p+1's MFMAs issue BEFORE packing
// pair p (pack's ~100 VALU cyc hides MFMA result latency); buffers refilled
// right after consumption. Named regs + unroll 1 -> no spill.
__global__ __launch_bounds__(512, 4) void vq_scan32(
    const float* __restrict__ z, const float* __restrict__ cb,
    const short8* __restrict__ cbb32, const short8* __restrict__ pka,
    float* __restrict__ out)
{
    __shared__ float sbest[NWAVE][ROWS_PB];
    __shared__ float lsum[NWAVE];

    const int tid  = threadIdx.x;
    const int lane = tid & 63;
    const int w    = tid >> 6;            // k-wave 0..7
    const int c32  = lane & 31;
    const int hi   = lane >> 5;

    const int row0 = blockIdx.x * ROWS_PB;

    // A frag: lanes 0..31 = row channels (k=0..7); lanes 32..63 = [1.0,0...] (k=8)
    short8 af;
    if (hi == 0) {
        af = pka[row0 + c32];
    } else {
        short8 one = {(short)0x3F80, 0, 0, 0, 0, 0, 0, 0};
        af = one;
    }

    const int kbase = w * (KCB / NWAVE);  // 1024 entries = 16 pairs of groups
    const char* bpc = (const char*)cbb32 + (size_t)kbase * 32
                    + (size_t)c32 * 16 + (size_t)hi * 512;

    float best[16];
    #pragma unroll
    for (int r = 0; r < 16; ++r)
        best[r] = __uint_as_float(0xFF800000u);   // -inf

    const f32x16 z16 = {0.f,0.f,0.f,0.f,0.f,0.f,0.f,0.f,
                        0.f,0.f,0.f,0.f,0.f,0.f,0.f,0.f};

#define LDP0(P) (*(const short8*)(bpc + (size_t)(P) * 2048))
#define LDP1(P) (*(const short8*)(bpc + (size_t)(P) * 2048 + 1024))
#define PACK16(D0, D1, IV)                                            \
    {   const unsigned iv0_ = (IV), iv1_ = (IV) - 32u;                \
        _Pragma("unroll")                                             \
        for (int r = 0; r < 16; ++r)                                  \
            packmax3(best[r], (D0)[r], (D1)[r], iv0_, iv1_);          }

    unsigned ivA = 8191u - (unsigned)kbase - (unsigned)c32;  // pair 0 base
    unsigned ivB = ivA - 64u;                                // pair 1 base

    // ---- prologue ----
    short8 bA0 = LDP0(0), bA1 = LDP1(0);
    short8 bB0 = LDP0(1), bB1 = LDP1(1);
    f32x16 dA0 = __builtin_amdgcn_mfma_f32_32x32x16_bf16(af, bA0, z16, 0, 0, 0);
    f32x16 dA1 = __builtin_amdgcn_mfma_f32_32x32x16_bf16(af, bA1, z16, 0, 0, 0);
    bA0 = LDP0(2); bA1 = LDP1(2);

    // ---- steady state: i handles pack(2i) and pack(2i+1) ----
    #pragma unroll 1
    for (int i = 0; i < 7; ++i) {
        f32x16 dB0 = __builtin_amdgcn_mfma_f32_32x32x16_bf16(af, bB0, z16, 0, 0, 0);
        f32x16 dB1 = __builtin_amdgcn_mfma_f32_32x32x16_bf16(af, bB1, z16, 0, 0, 0);
        bB0 = LDP0(2 * i + 3); bB1 = LDP1(2 * i + 3);
        PACK16(dA0, dA1, ivA);                 // covers dB latency
        ivA -= 128u;
        dA0 = __builtin_amdgcn_mfma_f32_32x32x16_bf16(af, bA0, z16, 0, 0, 0);
        dA1 = __builtin_amdgcn_mfma_f32_32x32x16_bf16(af, bA1, z16, 0, 0, 0);
        {   const int pn = (2 * i + 4) & 15;   // i=6 wraps -> dead load, harmless
            bA0 = LDP0(pn); bA1 = LDP1(pn); }
        PACK16(dB0, dB1, ivB);                 // covers dA latency
        ivB -= 128u;
    }

    // ---- epilogue: pairs 14 (in dA) and 15 (bB) ----
    {
        f32x16 dB0 = __builtin_amdgcn_mfma_f32_32x32x16_bf16(af, bB0, z16, 0, 0, 0);
        f32x16 dB1 = __builtin_amdgcn_mfma_f32_32x32x16_bf16(af, bB1, z16, 0, 0, 0);
        PACK16(dA0, dA1, ivA);
        PACK16(dB0, dB1, ivB);
    }

    // ---- reduce over 32 entry-cols ----
    #pragma unroll
    for (int d = 1; d < 32; d <<= 1)
        #pragma unroll
        for (int r = 0; r < 16; ++r)
            best[r] = fmaxf(best[r], __shfl_xor(best[r], d));

    if (c32 == 0) {
        #pragma unroll
        for (int r = 0; r < 16; ++r) {
            const int m = (r & 3) + ((r >> 2) << 3) + (hi << 2);  // C/D row map (verified)
            sbest[w][m] = best[r];
        }
    }
    __syncthreads();

    // ---- emit: 32 rows x 8 ch, one elem/thread (first 256 threads) ----
    float sq = 0.0f;
    if (tid < 256) {
        const int pos = tid & 31;
        const int ch  = tid >> 5;
        float m = sbest[0][pos];
        #pragma unroll
        for (int kw = 1; kw < NWAVE; ++kw) m = fmaxf(m, sbest[kw][pos]);
        const int k = 8191 - (int)(__float_as_uint(m) & 8191u);

        const int n = row0 + pos;
        const size_t o = ((size_t)(n >> 12)) * 32768 + (size_t)ch * 4096
                       + (size_t)(n & 4095);
        float ev = cb[(size_t)k * 8 + ch];
        float zz = z[o];
        out[o] = ev;
        float dd = ev - zz;
        sq = dd * dd;
    }
    #pragma unroll
    for (int off = 32; off > 0; off >>= 1) sq += __shfl_down(sq, off);
    if (lane == 0) lsum[w] = sq;
    __syncthreads();
    if (tid == 0) {
        float s = 0.f;
        #pragma unroll
        for (int kw = 0; kw < NWAVE; ++kw) s += lsum[kw];
        atomicAdd(out + NELEM, s * (1.25f / (float)NELEM));
    }
}

extern "C" void kernel_launch(void* const* d_in, const int* in_sizes, int n_in,
                              void* d_out, int out_size, void* d_ws, size_t ws_size,
                              hipStream_t stream)
{
    const float* z  = (const float*)d_in[0];   // [8, 8, 64, 64] fp32
    const float* cb = (const float*)d_in[1];   // [8192, 8] fp32
    float* out = (float*)d_out;                // 262144 z_q + 1 loss
    short8* cbb32 = (short8*)d_ws;                       // 256 KB packed codebook
    short8* pka   = (short8*)((char*)d_ws + 256 * 1024); // 512 KB packed z rows

    vq_prep<<<(KCB + NROWS) / 256, 256, 0, stream>>>(z, cb, cbb32, pka, out);
    vq_scan32<<<NROWS / ROWS_PB, 512, 0, stream>>>(z, cb, cbb32, pka, out);
}